// Round 7
// baseline (465.652 us; speedup 1.0000x reference)
//
#include <hip/hip_runtime.h>
#include <hip/hip_bf16.h>

// ---------- types / helpers ----------
typedef unsigned short u16;
typedef float f32x4 __attribute__((ext_vector_type(4)));
typedef __bf16 bf16x8 __attribute__((ext_vector_type(8)));
typedef unsigned short u16x8 __attribute__((ext_vector_type(8)));

__device__ __forceinline__ float b2f(u16 u) {
    unsigned v = ((unsigned)u) << 16;
    return __builtin_bit_cast(float, v);
}
__device__ __forceinline__ u16 f2b(float f) {
    unsigned u = __builtin_bit_cast(unsigned, f);
    u += 0x7fffu + ((u >> 16) & 1u);   // RNE
    return (u16)(u >> 16);
}
__device__ __forceinline__ bf16x8 ldfrag(const u16* p) {
    return __builtin_bit_cast(bf16x8, *(const u16x8*)p);
}
__device__ __forceinline__ f32x4 mfma16(bf16x8 a, bf16x8 b, f32x4 c) {
    return __builtin_amdgcn_mfma_f32_16x16x32_bf16(a, b, c, 0, 0, 0);
}
__device__ __forceinline__ void gload_lds16(const u16* g, u16* l) {
    __builtin_amdgcn_global_load_lds(
        (const __attribute__((address_space(1))) unsigned int*)(g),
        (__attribute__((address_space(3))) unsigned int*)(l), 16, 0, 0);
}

// ---------- problem constants ----------
#define T_TOK 8192
#define DM 768
#define NH 12
#define DH 64
#define DMLP 3072
#define SEQ 1024
#define QKV_LD 2304

// ---------- ws arena (u16 offsets) ----------
#define OFF_WQKV ((size_t)0)
#define OFF_WO   (OFF_WQKV + (size_t)2304*768)
#define OFF_WIN  (OFF_WO   + (size_t)768*768)
#define OFF_WOUT (OFF_WIN  + (size_t)768*3072)
#define OFF_BQKV (OFF_WOUT + (size_t)3072*768)          // float[2304] = 4608 u16
#define P0       (OFF_BQKV + (size_t)4608)

#define SZ_N    ((size_t)T_TOK*DM)        // 6,291,456
#define SZ_QKV  ((size_t)T_TOK*QKV_LD)    // 18,874,368
// Path A: resid_mid lives in d_out (fp32). Peak = P0 + nbuf + qkv + z = 77.1 MB
#define A_NBUF   (P0)
#define A_QKV    (P0 + SZ_N)
#define A_Z      (P0 + SZ_N + SZ_QKV)
#define A_N2     (P0)                       // overlays nbuf (dead after QKV GEMM)
#define A_POST   (P0 + SZ_N)                // overlays qkv+z (dead after O-proj); 25.17M u16 fits exactly
#define PATHA_BYTES (((size_t)(P0 + SZ_N + SZ_QKV + SZ_N)) * 2)
// Path B: per-batch attention, 2048-row MLP chunks. Peak = 44.0 MB
#define B_Z      (P0)
#define B_QKVB   (P0 + SZ_N)
#define B_NBUF   (B_QKVB + (size_t)SEQ*QKV_LD)
#define B_N2     (P0)                       // overlays z (dead after O-proj)
#define B_POSTC  (P0 + SZ_N)                // overlays qkvb+nbuf (dead after loop)

// ---------- prep: fp32 -> bf16 weight transposes + fp32 bias concat ----------
#define PR0 (2304*768)
#define PR1 (768*768)
#define PR2 (768*3072)
#define PR3 (3072*768)
#define PREP_TOTAL (PR0+PR1+PR2+PR3+2304)

__global__ __launch_bounds__(256) void prep_kernel(
    const float* __restrict__ WQ, const float* __restrict__ WK, const float* __restrict__ WV,
    const float* __restrict__ WO, const float* __restrict__ Win, const float* __restrict__ Wout,
    const float* __restrict__ bQ, const float* __restrict__ bK, const float* __restrict__ bV,
    u16* __restrict__ Wqkv_t, u16* __restrict__ Wo_t, u16* __restrict__ Win_t,
    u16* __restrict__ Wout_t, float* __restrict__ bias_qkv)
{
    int idx = blockIdx.x * 256 + threadIdx.x;
    if (idx < PR0) {
        int r = idx / 768, d = idx % 768;
        int which = r / 768;
        int he = r % 768;
        int h = he >> 6, e = he & 63;
        const float* W = (which == 0) ? WQ : ((which == 1) ? WK : WV);
        Wqkv_t[idx] = f2b(W[h * 49152 + d * 64 + e]);
    } else if (idx < PR0 + PR1) {
        int o = idx - PR0;
        int d = o / 768, he = o % 768;
        Wo_t[o] = f2b(WO[he * 768 + d]);
    } else if (idx < PR0 + PR1 + PR2) {
        int o = idx - PR0 - PR1;
        int m = o / 768, d = o % 768;
        Win_t[o] = f2b(Win[d * 3072 + m]);
    } else if (idx < PR0 + PR1 + PR2 + PR3) {
        int o = idx - PR0 - PR1 - PR2;
        int d = o / 3072, m = o % 3072;
        Wout_t[o] = f2b(Wout[m * 768 + d]);
    } else if (idx < PREP_TOTAL) {
        int j = idx - (PR0 + PR1 + PR2 + PR3);
        bias_qkv[j] = (j < 768) ? bQ[j] : ((j < 1536) ? bK[j - 768] : bV[j - 1536]);
    }
}

// ---------- layernorm (block per token), fp32 in -> bf16 out ----------
__global__ __launch_bounds__(256) void ln_kernel(
    const float* __restrict__ x, const float* __restrict__ w,
    const float* __restrict__ bb, u16* __restrict__ out)
{
    __shared__ float red[4];
    size_t base = (size_t)blockIdx.x * DM;
    int tid = threadIdx.x;
    float v0 = x[base + tid], v1 = x[base + tid + 256], v2 = x[base + tid + 512];
    float s = v0 + v1 + v2;
#pragma unroll
    for (int off = 32; off > 0; off >>= 1) s += __shfl_xor(s, off);
    if ((tid & 63) == 0) red[tid >> 6] = s;
    __syncthreads();
    float mu = (red[0] + red[1] + red[2] + red[3]) * (1.0f / 768.0f);
    v0 -= mu; v1 -= mu; v2 -= mu;
    float q = v0 * v0 + v1 * v1 + v2 * v2;
    __syncthreads();
#pragma unroll
    for (int off = 32; off > 0; off >>= 1) q += __shfl_xor(q, off);
    if ((tid & 63) == 0) red[tid >> 6] = q;
    __syncthreads();
    float var = (red[0] + red[1] + red[2] + red[3]) * (1.0f / 768.0f);
    float sc = rsqrtf(var + 1e-5f);
    out[base + tid]       = f2b(v0 * sc * w[tid]       + bb[tid]);
    out[base + tid + 256] = f2b(v1 * sc * w[tid + 256] + bb[tid + 256]);
    out[base + tid + 512] = f2b(v2 * sc * w[tid + 512] + bb[tid + 512]);
}

// ---------- GEMM: C[M][N] = A[M][K] @ BT[N][K]^T, m97-style ----------
// EPI 0: bf16 out = acc + bias
// EPI 1: f32  out = acc + bias + aux[row*N+col]     (resid_mid -> d_out)
// EPI 2: bf16 out = gelu_new(acc + bias)
// EPI 3: f32  out = acc + bias + aux[row*N+col]     (final, in-place over aux ok)
template <int EPI>
__global__ __launch_bounds__(256) void gemm_bt_kernel(
    const u16* __restrict__ A, const u16* __restrict__ BT,
    const float* __restrict__ bias, const float* __restrict__ aux,
    void* __restrict__ outp, int N, int K)
{
    __shared__ __align__(16) u16 As[128 * 32];
    __shared__ __align__(16) u16 Bs[128 * 32];
    const int tid = threadIdx.x;
    const int w = tid >> 6, l = tid & 63;
    const int lr = l & 15, lq = l >> 4;
    const int bm = blockIdx.x * 128, bn = blockIdx.y * 128;
    const int wm = (w >> 1) * 64, wn = (w & 1) * 64;

    f32x4 acc[4][4];
#pragma unroll
    for (int i = 0; i < 4; i++)
#pragma unroll
        for (int j = 0; j < 4; j++) acc[i][j] = f32x4{0.f, 0.f, 0.f, 0.f};

    const int srow = w * 32 + (l >> 2);
    const int scol = (l & 3) * 8;
    const u16* Ab = A  + (size_t)(bm + srow) * K + scol;
    const u16* Bb = BT + (size_t)(bn + srow) * K + scol;
    u16* AsD = As + w * 1024;
    u16* BsD = Bs + w * 1024;

    const int kiter = K >> 5;
    for (int kk = 0; kk < kiter; ++kk) {
        const int k0 = kk * 32;
        gload_lds16(Ab + k0,          AsD);
        gload_lds16(Ab + 16 * K + k0, AsD + 512);
        gload_lds16(Bb + k0,          BsD);
        gload_lds16(Bb + 16 * K + k0, BsD + 512);
        __syncthreads();
        bf16x8 af[4], bf[4];
#pragma unroll
        for (int mt = 0; mt < 4; mt++) af[mt] = ldfrag(&As[(wm + mt * 16 + lr) * 32 + lq * 8]);
#pragma unroll
        for (int nt = 0; nt < 4; nt++) bf[nt] = ldfrag(&Bs[(wn + nt * 16 + lr) * 32 + lq * 8]);
#pragma unroll
        for (int mt = 0; mt < 4; mt++)
#pragma unroll
            for (int nt = 0; nt < 4; nt++)
                acc[mt][nt] = mfma16(af[mt], bf[nt], acc[mt][nt]);
        __syncthreads();
    }

#pragma unroll
    for (int mt = 0; mt < 4; mt++) {
#pragma unroll
        for (int r = 0; r < 4; r++) {
            int row = bm + wm + mt * 16 + lq * 4 + r;
            size_t ro = (size_t)row * N;
#pragma unroll
            for (int nt = 0; nt < 4; nt++) {
                int col = bn + wn + nt * 16 + lr;
                float v = acc[mt][nt][r] + bias[col];
                if (EPI == 0) {
                    ((u16*)outp)[ro + col] = f2b(v);
                } else if (EPI == 1) {
                    ((float*)outp)[ro + col] = v + aux[ro + col];
                } else if (EPI == 2) {
                    float x = v;
                    float t = tanhf(0.7978845608028654f * (x + 0.044715f * x * x * x));
                    ((u16*)outp)[ro + col] = f2b(0.5f * x * (1.0f + t));
                } else {
                    ((float*)outp)[ro + col] = v + aux[ro + col];
                }
            }
        }
    }
}

// ---------- flash attention (MFMA): block = (64 q-rows, batch*head) ----------
__global__ __launch_bounds__(256) void attn_kernel(
    const u16* __restrict__ qkv, u16* __restrict__ z, int b0, int bq0)
{
    __shared__ __align__(16) u16 Qs[64 * 72];
    __shared__ __align__(16) u16 Ks[128 * 72];
    __shared__ __align__(16) u16 Vt[64 * 136];
    __shared__ __align__(16) u16 Ps[4][16 * 136];

    const int qt = blockIdx.x, bh = blockIdx.y;
    const int b = b0 + bh / NH, h = bh % NH;
    const int tid = threadIdx.x, w = tid >> 6, l = tid & 63;
    const int lr = l & 15, lq = l >> 4;
    const int qbase = qt * 64;
    const u16* qp = qkv + (size_t)(b - bq0) * SEQ * QKV_LD + h * 64;
    const u16* kp = qp + 768;
    const u16* vp = qp + 1536;

    {
        int row = tid >> 2, cg = (tid & 3) * 16;
        const u16* src = qp + (size_t)(qbase + row) * QKV_LD + cg;
        *(u16x8*)&Qs[row * 72 + cg]     = *(const u16x8*)src;
        *(u16x8*)&Qs[row * 72 + cg + 8] = *(const u16x8*)(src + 8);
    }

    float m_i[4] = {-1e30f, -1e30f, -1e30f, -1e30f};
    float l_i[4] = {0.f, 0.f, 0.f, 0.f};
    f32x4 O[4];
#pragma unroll
    for (int i = 0; i < 4; i++) O[i] = f32x4{0.f, 0.f, 0.f, 0.f};

    const int nkt = (qbase + 191) >> 7;
    const int krow = tid >> 1, kcg = (tid & 1) * 32;

    for (int kt = 0; kt < nkt; ++kt) {
        __syncthreads();
        {
            const u16* ks = kp + (size_t)(kt * 128 + krow) * QKV_LD + kcg;
#pragma unroll
            for (int j = 0; j < 4; j++)
                *(u16x8*)&Ks[krow * 72 + kcg + j * 8] = *(const u16x8*)(ks + j * 8);
            const u16* vs = vp + (size_t)(kt * 128 + krow) * QKV_LD + kcg;
            u16x8 tv[4];
#pragma unroll
            for (int j = 0; j < 4; j++) tv[j] = *(const u16x8*)(vs + j * 8);
#pragma unroll
            for (int j = 0; j < 4; j++)
#pragma unroll
                for (int e = 0; e < 8; e++)
                    Vt[(kcg + j * 8 + e) * 136 + krow] = tv[j][e];
        }
        __syncthreads();

        f32x4 S[8];
#pragma unroll
        for (int nt = 0; nt < 8; nt++) S[nt] = f32x4{0.f, 0.f, 0.f, 0.f};
#pragma unroll
        for (int d0 = 0; d0 < 64; d0 += 32) {
            bf16x8 aq = ldfrag(&Qs[(w * 16 + lr) * 72 + d0 + lq * 8]);
#pragma unroll
            for (int nt = 0; nt < 8; nt++) {
                bf16x8 bk = ldfrag(&Ks[(nt * 16 + lr) * 72 + d0 + lq * 8]);
                S[nt] = mfma16(aq, bk, S[nt]);
            }
        }

        const int kb = kt * 128;
#pragma unroll
        for (int r = 0; r < 4; r++) {
            int q = qbase + w * 16 + lq * 4 + r;
            float pv[8];
            float mx = -1e30f;
#pragma unroll
            for (int nt = 0; nt < 8; nt++) {
                int kpos = kb + nt * 16 + lr;
                float sv = (kpos <= q) ? S[nt][r] * 0.125f : -1e30f;
                pv[nt] = sv;
                mx = fmaxf(mx, sv);
            }
            mx = fmaxf(mx, __shfl_xor(mx, 1));
            mx = fmaxf(mx, __shfl_xor(mx, 2));
            mx = fmaxf(mx, __shfl_xor(mx, 4));
            mx = fmaxf(mx, __shfl_xor(mx, 8));
            float mn = fmaxf(m_i[r], mx);
            float alpha = __expf(m_i[r] - mn);
            m_i[r] = mn;
            l_i[r] *= alpha;
            O[0][r] *= alpha; O[1][r] *= alpha; O[2][r] *= alpha; O[3][r] *= alpha;
            float rs = 0.f;
#pragma unroll
            for (int nt = 0; nt < 8; nt++) {
                float p = __expf(pv[nt] - mn);
                rs += p;
                Ps[w][(lq * 4 + r) * 136 + nt * 16 + lr] = f2b(p);
            }
            rs += __shfl_xor(rs, 1);
            rs += __shfl_xor(rs, 2);
            rs += __shfl_xor(rs, 4);
            rs += __shfl_xor(rs, 8);
            l_i[r] += rs;
        }

#pragma unroll
        for (int kp0 = 0; kp0 < 128; kp0 += 32) {
            bf16x8 ap = ldfrag(&Ps[w][lr * 136 + kp0 + lq * 8]);
#pragma unroll
            for (int ot = 0; ot < 4; ot++) {
                bf16x8 bv = ldfrag(&Vt[(ot * 16 + lr) * 136 + kp0 + lq * 8]);
                O[ot] = mfma16(ap, bv, O[ot]);
            }
        }
    }

#pragma unroll
    for (int ot = 0; ot < 4; ot++)
#pragma unroll
        for (int r = 0; r < 4; r++) {
            int q = qbase + w * 16 + lq * 4 + r;
            size_t t = (size_t)b * SEQ + q;
            z[t * DM + h * 64 + ot * 16 + lr] = f2b(O[ot][r] / l_i[r]);
        }
}

// ---------- launch ----------
extern "C" void kernel_launch(void* const* d_in, const int* in_sizes, int n_in,
                              void* d_out, int out_size, void* d_ws, size_t ws_size,
                              hipStream_t stream) {
    const float* resid_pre = (const float*)d_in[0];
    const float* W_Q  = (const float*)d_in[1];
    const float* b_Q  = (const float*)d_in[2];
    const float* W_K  = (const float*)d_in[3];
    const float* b_K  = (const float*)d_in[4];
    const float* W_V  = (const float*)d_in[5];
    const float* b_V  = (const float*)d_in[6];
    const float* W_O  = (const float*)d_in[7];
    const float* b_O  = (const float*)d_in[8];
    const float* ln1w = (const float*)d_in[9];
    const float* ln1b = (const float*)d_in[10];
    const float* ln2w = (const float*)d_in[11];
    const float* ln2b = (const float*)d_in[12];
    const float* W_in  = (const float*)d_in[13];
    const float* b_in  = (const float*)d_in[14];
    const float* W_out = (const float*)d_in[15];
    const float* b_out = (const float*)d_in[16];

    u16* ws16       = (u16*)d_ws;
    u16* Wqkv_t     = ws16 + OFF_WQKV;
    u16* Wo_t       = ws16 + OFF_WO;
    u16* Win_t      = ws16 + OFF_WIN;
    u16* Wout_t     = ws16 + OFF_WOUT;
    float* bias_qkv = (float*)(ws16 + OFF_BQKV);
    float* outp  = (float*)d_out;    // fp32 output (reference dtype)
    float* resid = (float*)d_out;    // resid_mid lives in d_out until final add

    prep_kernel<<<(PREP_TOTAL + 255) / 256, 256, 0, stream>>>(
        W_Q, W_K, W_V, W_O, W_in, W_out, b_Q, b_K, b_V,
        Wqkv_t, Wo_t, Win_t, Wout_t, bias_qkv);

    if (ws_size >= PATHA_BYTES) {
        // ---- Path A (77 MB ws) ----
        u16* nbuf    = ws16 + A_NBUF;
        u16* qkvbuf  = ws16 + A_QKV;
        u16* zbuf    = ws16 + A_Z;
        u16* n2buf   = ws16 + A_N2;
        u16* postbuf = ws16 + A_POST;

        ln_kernel<<<T_TOK, 256, 0, stream>>>(resid_pre, ln1w, ln1b, nbuf);
        gemm_bt_kernel<0><<<dim3(T_TOK / 128, QKV_LD / 128), 256, 0, stream>>>(
            nbuf, Wqkv_t, bias_qkv, nullptr, qkvbuf, QKV_LD, DM);
        attn_kernel<<<dim3(SEQ / 64, 8 * NH), 256, 0, stream>>>(qkvbuf, zbuf, 0, 0);
        gemm_bt_kernel<1><<<dim3(T_TOK / 128, DM / 128), 256, 0, stream>>>(
            zbuf, Wo_t, b_O, resid_pre, resid, DM, DM);
        ln_kernel<<<T_TOK, 256, 0, stream>>>(resid, ln2w, ln2b, n2buf);
        gemm_bt_kernel<2><<<dim3(T_TOK / 128, DMLP / 128), 256, 0, stream>>>(
            n2buf, Win_t, b_in, nullptr, postbuf, DMLP, DM);
        gemm_bt_kernel<3><<<dim3(T_TOK / 128, DM / 128), 256, 0, stream>>>(
            postbuf, Wout_t, b_out, resid, outp, DM, DMLP);
    } else {
        // ---- Path B (44 MB ws): per-batch attention, chunked MLP ----
        u16* zbuf   = ws16 + B_Z;
        u16* qkvb   = ws16 + B_QKVB;
        u16* nbuf   = ws16 + B_NBUF;
        u16* n2buf  = ws16 + B_N2;
        u16* postc  = ws16 + B_POSTC;

        ln_kernel<<<T_TOK, 256, 0, stream>>>(resid_pre, ln1w, ln1b, nbuf);
        for (int b = 0; b < 8; b++) {
            gemm_bt_kernel<0><<<dim3(SEQ / 128, QKV_LD / 128), 256, 0, stream>>>(
                nbuf + (size_t)b * SEQ * DM, Wqkv_t, bias_qkv, nullptr, qkvb, QKV_LD, DM);
            attn_kernel<<<dim3(SEQ / 64, NH), 256, 0, stream>>>(qkvb, zbuf, b, b);
        }
        gemm_bt_kernel<1><<<dim3(T_TOK / 128, DM / 128), 256, 0, stream>>>(
            zbuf, Wo_t, b_O, resid_pre, resid, DM, DM);
        ln_kernel<<<T_TOK, 256, 0, stream>>>(resid, ln2w, ln2b, n2buf);
        for (int c = 0; c < 4; c++) {
            const size_t r0 = (size_t)c * 2048;
            gemm_bt_kernel<2><<<dim3(2048 / 128, DMLP / 128), 256, 0, stream>>>(
                n2buf + r0 * DM, Win_t, b_in, nullptr, postc, DMLP, DM);
            gemm_bt_kernel<3><<<dim3(2048 / 128, DM / 128), 256, 0, stream>>>(
                postc, Wout_t, b_out, resid + r0 * DM, outp + r0 * DM, DM, DMLP);
        }
    }
}